// Round 1
// baseline (735.677 us; speedup 1.0000x reference)
//
#include <hip/hip_runtime.h>
#include <math.h>

#define L_NODES 16384
#define EMB 512
#define NHEAD 8
#define HDIM 64
#define DEG 16
#define NNZ_E (L_NODES * DEG)

#define TILE 64
#define BKK 16
#define PAD_LD 68   // 68 floats = 272 B row stride: keeps 16B alignment, <=2-way bank alias

// C[M x N] = (A[M x K] @ W^T + bias) * scale ; W is N x K row-major (torch Linear)
__global__ __launch_bounds__(256) void gemm_bt(
    const float* __restrict__ A,
    const float* __restrict__ W,
    const float* __restrict__ bias,
    float* __restrict__ C,
    int M, int K, int N, float scale)
{
    __shared__ float As[BKK][PAD_LD];
    __shared__ float Bs[BKK][PAD_LD];

    const int t  = threadIdx.x;
    const int tx = t & 15;        // 0..15 -> 4 cols each
    const int ty = t >> 4;        // 0..15 -> 4 rows each
    const int row0 = blockIdx.y * TILE;
    const int col0 = blockIdx.x * TILE;

    // staging: each thread loads one float4 of A-tile and one of W-tile
    const int lr = t >> 2;          // 0..63 (row within tile)
    const int lk = (t & 3) << 2;    // 0,4,8,12 (k offset)

    const float* Aptr = A + (size_t)(row0 + lr) * K + lk;
    const float* Wptr = W + (size_t)(col0 + lr) * K + lk;

    float acc[4][4] = {};

    for (int k0 = 0; k0 < K; k0 += BKK) {
        float4 a4 = *reinterpret_cast<const float4*>(Aptr + k0);
        float4 b4 = *reinterpret_cast<const float4*>(Wptr + k0);
        As[lk + 0][lr] = a4.x; As[lk + 1][lr] = a4.y;
        As[lk + 2][lr] = a4.z; As[lk + 3][lr] = a4.w;
        Bs[lk + 0][lr] = b4.x; Bs[lk + 1][lr] = b4.y;
        Bs[lk + 2][lr] = b4.z; Bs[lk + 3][lr] = b4.w;
        __syncthreads();

#pragma unroll
        for (int kk = 0; kk < BKK; ++kk) {
            float a[4], b[4];
#pragma unroll
            for (int i2 = 0; i2 < 4; ++i2) a[i2] = As[kk][ty * 4 + i2];
#pragma unroll
            for (int j2 = 0; j2 < 4; ++j2) b[j2] = Bs[kk][tx * 4 + j2];
#pragma unroll
            for (int i2 = 0; i2 < 4; ++i2)
#pragma unroll
                for (int j2 = 0; j2 < 4; ++j2)
                    acc[i2][j2] += a[i2] * b[j2];
        }
        __syncthreads();
    }

#pragma unroll
    for (int i2 = 0; i2 < 4; ++i2) {
        const int r = row0 + ty * 4 + i2;
        float4 o;
        o.x = (acc[i2][0] + bias[col0 + tx * 4 + 0]) * scale;
        o.y = (acc[i2][1] + bias[col0 + tx * 4 + 1]) * scale;
        o.z = (acc[i2][2] + bias[col0 + tx * 4 + 2]) * scale;
        o.w = (acc[i2][3] + bias[col0 + tx * 4 + 3]) * scale;
        *reinterpret_cast<float4*>(&C[(size_t)r * N + col0 + tx * 4]) = o;
    }
}

// One block per node; wave w = head h; lane = d in [0,64).
// out may alias q (block i reads q-row i before writing out-row i; no other
// block touches row i of q) -> q/out deliberately NOT __restrict__.
__global__ __launch_bounds__(512) void edge_attn(
    const float* q, const float* __restrict__ kmat, const float* __restrict__ vmat,
    const int* __restrict__ colidx, float* out)
{
    const int i    = blockIdx.x;
    const int h    = threadIdx.x >> 6;
    const int lane = threadIdx.x & 63;
    const size_t base = (size_t)i * EMB + h * HDIM + lane;

    const float qd = q[base];  // q already scaled by 1/sqrt(D)

    int creg = 0;
    if (lane < DEG) creg = colidx[i * DEG + lane];

    float s[DEG];
#pragma unroll
    for (int e = 0; e < DEG; ++e) {
        const int ce = __shfl(creg, e, 64);
        float p = qd * kmat[(size_t)ce * EMB + h * HDIM + lane];
#pragma unroll
        for (int off = 32; off; off >>= 1) p += __shfl_xor(p, off, 64);
        s[e] = p;   // full sum broadcast to all lanes
    }

    float m = s[0];
#pragma unroll
    for (int e = 1; e < DEG; ++e) m = fmaxf(m, s[e]);

    float denom = 0.f;
#pragma unroll
    for (int e = 0; e < DEG; ++e) { s[e] = expf(s[e] - m); denom += s[e]; }
    const float inv = 1.f / denom;

    float o = 0.f;
#pragma unroll
    for (int e = 0; e < DEG; ++e) {
        const int ce = __shfl(creg, e, 64);
        o += s[e] * vmat[(size_t)ce * EMB + h * HDIM + lane];
    }
    out[base] = o * inv;
}

extern "C" void kernel_launch(void* const* d_in, const int* in_sizes, int n_in,
                              void* d_out, int out_size, void* d_ws, size_t ws_size,
                              hipStream_t stream) {
    const float* query  = (const float*)d_in[0];
    const float* key_   = (const float*)d_in[1];
    const float* value  = (const float*)d_in[2];
    const int*   indices= (const int*)  d_in[3];   // (2, NNZ) int32; col = +NNZ
    const float* ipw    = (const float*)d_in[4];   // (1536, 512)
    const float* ipb    = (const float*)d_in[5];   // (1536,)
    const float* opw    = (const float*)d_in[6];   // (512, 512)
    const float* opb    = (const float*)d_in[7];   // (512,)
    float* out = (float*)d_out;

    float* qbuf = (float*)d_ws;
    float* kbuf = qbuf + (size_t)L_NODES * EMB;
    float* vbuf = kbuf + (size_t)L_NODES * EMB;
    float* attn = qbuf;  // alias: safe (see edge_attn comment)

    const dim3 gblk(EMB / TILE, L_NODES / TILE);
    const float scaling = 0.125f;  // 1/sqrt(64)

    gemm_bt<<<gblk, 256, 0, stream>>>(query, ipw,                 ipb,           qbuf,
                                      L_NODES, EMB, EMB, scaling);
    gemm_bt<<<gblk, 256, 0, stream>>>(key_,  ipw + 1 * EMB * EMB, ipb + 1 * EMB, kbuf,
                                      L_NODES, EMB, EMB, 1.f);
    gemm_bt<<<gblk, 256, 0, stream>>>(value, ipw + 2 * EMB * EMB, ipb + 2 * EMB, vbuf,
                                      L_NODES, EMB, EMB, 1.f);

    edge_attn<<<L_NODES, 512, 0, stream>>>(qbuf, kbuf, vbuf, indices + NNZ_E, attn);

    gemm_bt<<<gblk, 256, 0, stream>>>(attn, opw, opb, out, L_NODES, EMB, EMB, 1.f);
}

// Round 4
// 271.275 us; speedup vs baseline: 2.7119x; 2.7119x over previous
//
#include <hip/hip_runtime.h>
#include <math.h>

#define L_NODES 16384
#define EMB 512
#define NHEAD 8
#define HDIM 64
#define DEG 16
#define NNZ_E (L_NODES * DEG)

typedef __attribute__((ext_vector_type(8))) short short8;
typedef __attribute__((ext_vector_type(4))) float f32x4;

// ---------------- fp32 -> bf16 convert (RNE) ----------------
__device__ inline short f2bs(float x) {
    union { float f; unsigned u; } c; c.f = x;
    unsigned r = (c.u + 0x7fffu + ((c.u >> 16) & 1u)) >> 16;
    return (short)r;
}

__global__ __launch_bounds__(256) void f2b(const float* __restrict__ s,
                                           short* __restrict__ d, int n8) {
    const int stride = gridDim.x * blockDim.x;
    for (int i = blockIdx.x * blockDim.x + threadIdx.x; i < n8; i += stride) {
        float4 a = reinterpret_cast<const float4*>(s)[2 * i];
        float4 b = reinterpret_cast<const float4*>(s)[2 * i + 1];
        short8 o;
        o[0] = f2bs(a.x); o[1] = f2bs(a.y); o[2] = f2bs(a.z); o[3] = f2bs(a.w);
        o[4] = f2bs(b.x); o[5] = f2bs(b.y); o[6] = f2bs(b.z); o[7] = f2bs(b.w);
        reinterpret_cast<short8*>(d)[i] = o;
    }
}

// ---------------- bf16 MFMA GEMM: C = (A @ B^T + bias) * scale ----------------
// A: M x K bf16 row-major; B: N x K bf16 row-major (torch Linear weight)
#define BM 128
#define BN 128
#define GBK 32

__device__ inline void gload16(const short* g, short* l) {
    __builtin_amdgcn_global_load_lds(
        (const __attribute__((address_space(1))) unsigned*)g,
        (__attribute__((address_space(3))) unsigned*)l, 16, 0, 0);
}

__global__ __launch_bounds__(256) void gemm_bf16(
    const short* __restrict__ A, const short* __restrict__ B,
    const float* __restrict__ bias, float* __restrict__ C,
    int M, int K, int N, float scale)
{
    __shared__ __align__(16) short As[BM * GBK];
    __shared__ __align__(16) short Bs[BN * GBK];

    const int t    = threadIdx.x;
    const int wid  = t >> 6;
    const int lane = t & 63;

    // bijective XCD swizzle (gridDim.x % 8 == 0): each XCD gets a contiguous chunk
    const int cpx = gridDim.x >> 3;
    const int bid = blockIdx.x;
    const int wg  = (bid & 7) * cpx + (bid >> 3);
    const int nbx = N / BN;                 // 4 for N=512 (power of 2)
    const int bx  = wg & (nbx - 1);
    const int by  = wg / nbx;

    const int row0 = by * BM;
    const int col0 = bx * BN;

    // staging map: thread t covers (row sr, 16B k-slot), slot XOR-swizzled so the
    // ds_read_b128 fragment reads are <=2-way bank conflicts. LDS stays linear
    // (global_load_lds requirement); the swizzle is applied on the GLOBAL source.
    const int sr = t >> 2;                      // 0..63
    const int ss = (t & 3) ^ ((sr >> 1) & 3);   // logical k-slot stored at lds slot t&3
    const short* Ag0 = A + (size_t)(row0 + sr) * K + ss * 8;
    const short* Ag1 = A + (size_t)(row0 + 64 + sr) * K + ss * 8;
    const short* Bg0 = B + (size_t)(col0 + sr) * K + ss * 8;
    const short* Bg1 = B + (size_t)(col0 + 64 + sr) * K + ss * 8;
    short* Al0 = &As[wid * 512];
    short* Al1 = &As[2048 + wid * 512];
    short* Bl0 = &Bs[wid * 512];
    short* Bl1 = &Bs[2048 + wid * 512];

    const int wr = wid >> 1, wc = wid & 1;      // wave -> 64x64 quadrant

    f32x4 acc[4][4] = {};

    for (int k0 = 0; k0 < K; k0 += GBK) {
        gload16(Ag0 + k0, Al0);
        gload16(Ag1 + k0, Al1);
        gload16(Bg0 + k0, Bl0);
        gload16(Bg1 + k0, Bl1);
        __syncthreads();

        short8 af[4], bf[4];
#pragma unroll
        for (int i = 0; i < 4; ++i) {
            const int r  = wr * 64 + i * 16 + (lane & 15);
            const int sl = (lane >> 4) ^ ((r >> 1) & 3);
            af[i] = *reinterpret_cast<const short8*>(&As[r * GBK + sl * 8]);
        }
#pragma unroll
        for (int j = 0; j < 4; ++j) {
            const int r  = wc * 64 + j * 16 + (lane & 15);
            const int sl = (lane >> 4) ^ ((r >> 1) & 3);
            bf[j] = *reinterpret_cast<const short8*>(&Bs[r * GBK + sl * 8]);
        }
#pragma unroll
        for (int i = 0; i < 4; ++i)
#pragma unroll
            for (int j = 0; j < 4; ++j)
                acc[i][j] = __builtin_amdgcn_mfma_f32_16x16x32_bf16(
                    af[i], bf[j], acc[i][j], 0, 0, 0);
        __syncthreads();
    }

    // epilogue: C/D layout col=lane&15, row=(lane>>4)*4+reg (m89/m91 verified)
    float bv[4];
#pragma unroll
    for (int j = 0; j < 4; ++j) bv[j] = bias[col0 + wc * 64 + j * 16 + (lane & 15)];
#pragma unroll
    for (int i = 0; i < 4; ++i) {
        const int rbase = row0 + wr * 64 + i * 16 + (lane >> 4) * 4;
#pragma unroll
        for (int j = 0; j < 4; ++j) {
            const int col = col0 + wc * 64 + j * 16 + (lane & 15);
#pragma unroll
            for (int rg = 0; rg < 4; ++rg)
                C[(size_t)(rbase + rg) * N + col] = (acc[i][j][rg] + bv[j]) * scale;
        }
    }
}

// ---------------- fp32 fallback GEMM (ws too small for bf16 path) ----------------
#define TILE 64
#define BKK 16
#define PAD_LD 68

__global__ __launch_bounds__(256) void gemm_bt(
    const float* __restrict__ A, const float* __restrict__ W,
    const float* __restrict__ bias, float* __restrict__ C,
    int M, int K, int N, float scale)
{
    __shared__ float Asm[BKK][PAD_LD];
    __shared__ float Bsm[BKK][PAD_LD];
    const int t  = threadIdx.x;
    const int tx = t & 15;
    const int ty = t >> 4;
    const int row0 = blockIdx.y * TILE;
    const int col0 = blockIdx.x * TILE;
    const int lr = t >> 2;
    const int lk = (t & 3) << 2;
    const float* Aptr = A + (size_t)(row0 + lr) * K + lk;
    const float* Wptr = W + (size_t)(col0 + lr) * K + lk;
    float acc[4][4] = {};
    for (int k0 = 0; k0 < K; k0 += BKK) {
        float4 a4 = *reinterpret_cast<const float4*>(Aptr + k0);
        float4 b4 = *reinterpret_cast<const float4*>(Wptr + k0);
        Asm[lk + 0][lr] = a4.x; Asm[lk + 1][lr] = a4.y;
        Asm[lk + 2][lr] = a4.z; Asm[lk + 3][lr] = a4.w;
        Bsm[lk + 0][lr] = b4.x; Bsm[lk + 1][lr] = b4.y;
        Bsm[lk + 2][lr] = b4.z; Bsm[lk + 3][lr] = b4.w;
        __syncthreads();
#pragma unroll
        for (int kk = 0; kk < BKK; ++kk) {
            float a[4], b[4];
#pragma unroll
            for (int i2 = 0; i2 < 4; ++i2) a[i2] = Asm[kk][ty * 4 + i2];
#pragma unroll
            for (int j2 = 0; j2 < 4; ++j2) b[j2] = Bsm[kk][tx * 4 + j2];
#pragma unroll
            for (int i2 = 0; i2 < 4; ++i2)
#pragma unroll
                for (int j2 = 0; j2 < 4; ++j2)
                    acc[i2][j2] += a[i2] * b[j2];
        }
        __syncthreads();
    }
#pragma unroll
    for (int i2 = 0; i2 < 4; ++i2) {
        const int r = row0 + ty * 4 + i2;
        float4 o;
        o.x = (acc[i2][0] + bias[col0 + tx * 4 + 0]) * scale;
        o.y = (acc[i2][1] + bias[col0 + tx * 4 + 1]) * scale;
        o.z = (acc[i2][2] + bias[col0 + tx * 4 + 2]) * scale;
        o.w = (acc[i2][3] + bias[col0 + tx * 4 + 3]) * scale;
        *reinterpret_cast<float4*>(&C[(size_t)r * N + col0 + tx * 4]) = o;
    }
}

// ---------------- edge softmax/aggregate ----------------
// One block per node; wave = head; lane = d. Prefetch ALL 16 K rows and 16 V rows
// into registers before any reduction (32 loads in flight -> one latency exposure).
// out may alias q (block i reads q-row i before writing it) -> not __restrict__.
__global__ __launch_bounds__(512) void edge_attn(
    const float* q, const float* __restrict__ kmat, const float* __restrict__ vmat,
    const int* __restrict__ colidx, float* out)
{
    const int i    = blockIdx.x;
    const int h    = threadIdx.x >> 6;
    const int lane = threadIdx.x & 63;
    const size_t base = (size_t)i * EMB + h * HDIM + lane;

    const float qd = q[base];  // q pre-scaled by 1/sqrt(D)
    int creg = 0;
    if (lane < DEG) creg = colidx[i * DEG + lane];

    float kr[DEG], vr[DEG];
#pragma unroll
    for (int e = 0; e < DEG; ++e) {
        const int ce = __shfl(creg, e, 64);
        const size_t cb = (size_t)ce * EMB + h * HDIM + lane;
        kr[e] = kmat[cb];
        vr[e] = vmat[cb];
    }

    float s[DEG];
#pragma unroll
    for (int e = 0; e < DEG; ++e) {
        float p = qd * kr[e];
#pragma unroll
        for (int off = 32; off; off >>= 1) p += __shfl_xor(p, off, 64);
        s[e] = p;
    }

    float m = s[0];
#pragma unroll
    for (int e = 1; e < DEG; ++e) m = fmaxf(m, s[e]);

    float denom = 0.f;
#pragma unroll
    for (int e = 0; e < DEG; ++e) { s[e] = expf(s[e] - m); denom += s[e]; }
    const float inv = 1.f / denom;

    float o = 0.f;
#pragma unroll
    for (int e = 0; e < DEG; ++e) o += s[e] * vr[e];
    out[base] = o * inv;
}

extern "C" void kernel_launch(void* const* d_in, const int* in_sizes, int n_in,
                              void* d_out, int out_size, void* d_ws, size_t ws_size,
                              hipStream_t stream) {
    const float* query   = (const float*)d_in[0];
    const float* key_    = (const float*)d_in[1];
    const float* value   = (const float*)d_in[2];
    const int*   indices = (const int*)  d_in[3];   // (2, NNZ) int32; col = +NNZ
    const float* ipw     = (const float*)d_in[4];   // (1536, 512)
    const float* ipb     = (const float*)d_in[5];
    const float* opw     = (const float*)d_in[6];   // (512, 512)
    const float* opb     = (const float*)d_in[7];
    float* out = (float*)d_out;

    const float scaling = 0.125f;  // 1/sqrt(64)
    const size_t NEED_BF16 = 153092096;  // 3x bf16 in + bf16 weights + 3x fp32 proj

    if (ws_size >= NEED_BF16) {
        short* qb   = (short*)d_ws;          // 8388608 shorts
        short* kb   = qb + 8388608;
        short* vb   = kb + 8388608;
        short* wqkv = vb + 8388608;          // 786432 shorts
        short* wo   = wqkv + 786432;         // 262144 shorts
        float* qf   = (float*)((char*)d_ws + 52428800);
        float* kf   = qf + 8388608;
        float* vf   = kf + 8388608;

        f2b<<<2048, 256, 0, stream>>>(query, qb, 1048576);
        f2b<<<2048, 256, 0, stream>>>(key_,  kb, 1048576);
        f2b<<<2048, 256, 0, stream>>>(value, vb, 1048576);
        f2b<<<384,  256, 0, stream>>>(ipw, wqkv, 98304);
        f2b<<<128,  256, 0, stream>>>(opw, wo,   32768);

        gemm_bf16<<<512, 256, 0, stream>>>(qb, wqkv,          ipb,        qf,
                                           L_NODES, EMB, EMB, scaling);
        gemm_bf16<<<512, 256, 0, stream>>>(kb, wqkv + 262144, ipb + 512,  kf,
                                           L_NODES, EMB, EMB, 1.f);
        gemm_bf16<<<512, 256, 0, stream>>>(vb, wqkv + 524288, ipb + 1024, vf,
                                           L_NODES, EMB, EMB, 1.f);

        edge_attn<<<L_NODES, 512, 0, stream>>>(qf, kf, vf, indices + NNZ_E, qf);

        f2b<<<2048, 256, 0, stream>>>(qf, qb, 1048576);   // attn -> bf16 (reuse qb)
        gemm_bf16<<<512, 256, 0, stream>>>(qb, wo, opb, out, L_NODES, EMB, EMB, 1.f);
    } else {
        float* qbuf = (float*)d_ws;
        float* kbuf = qbuf + (size_t)L_NODES * EMB;
        float* vbuf = kbuf + (size_t)L_NODES * EMB;
        const dim3 gblk(EMB / TILE, L_NODES / TILE);
        gemm_bt<<<gblk, 256, 0, stream>>>(query, ipw,               ipb,        qbuf,
                                          L_NODES, EMB, EMB, scaling);
        gemm_bt<<<gblk, 256, 0, stream>>>(key_,  ipw + 1 * EMB * EMB, ipb + EMB,  kbuf,
                                          L_NODES, EMB, EMB, 1.f);
        gemm_bt<<<gblk, 256, 0, stream>>>(value, ipw + 2 * EMB * EMB, ipb + 2*EMB, vbuf,
                                          L_NODES, EMB, EMB, 1.f);
        edge_attn<<<L_NODES, 512, 0, stream>>>(qbuf, kbuf, vbuf, indices + NNZ_E, qbuf);
        gemm_bt<<<gblk, 256, 0, stream>>>(qbuf, opw, opb, out, L_NODES, EMB, EMB, 1.f);
    }
}

// Round 5
// 258.619 us; speedup vs baseline: 2.8446x; 1.0489x over previous
//
#include <hip/hip_runtime.h>
#include <math.h>

#define L_NODES 16384
#define EMB 512
#define NHEAD 8
#define HDIM 64
#define DEG 16
#define NNZ_E (L_NODES * DEG)

typedef __attribute__((ext_vector_type(8))) short short8;
typedef __attribute__((ext_vector_type(4))) short short4v;
typedef __attribute__((ext_vector_type(4))) float f32x4;

// ---------------- fp32 -> bf16 convert (RNE) ----------------
__device__ inline short f2bs(float x) {
    union { float f; unsigned u; } c; c.f = x;
    unsigned r = (c.u + 0x7fffu + ((c.u >> 16) & 1u)) >> 16;
    return (short)r;
}

__global__ __launch_bounds__(256) void f2b(const float* __restrict__ s,
                                           short* __restrict__ d, int n8) {
    const int stride = gridDim.x * blockDim.x;
    for (int i = blockIdx.x * blockDim.x + threadIdx.x; i < n8; i += stride) {
        float4 a = reinterpret_cast<const float4*>(s)[2 * i];
        float4 b = reinterpret_cast<const float4*>(s)[2 * i + 1];
        short8 o;
        o[0] = f2bs(a.x); o[1] = f2bs(a.y); o[2] = f2bs(a.z); o[3] = f2bs(a.w);
        o[4] = f2bs(b.x); o[5] = f2bs(b.y); o[6] = f2bs(b.z); o[7] = f2bs(b.w);
        reinterpret_cast<short8*>(d)[i] = o;
    }
}

// ---------------- bf16 MFMA GEMM: C = (A @ B^T + bias) * scale ----------------
#define BM 128
#define BN 128
#define GBK 32

__device__ inline void gload16(const short* g, short* l) {
    __builtin_amdgcn_global_load_lds(
        (const __attribute__((address_space(1))) unsigned*)g,
        (__attribute__((address_space(3))) unsigned*)l, 16, 0, 0);
}

__global__ __launch_bounds__(256) void gemm_bf16(
    const short* __restrict__ A, const short* __restrict__ B,
    const float* __restrict__ bias, float* __restrict__ C,
    int M, int K, int N, float scale)
{
    __shared__ __align__(16) short As[BM * GBK];
    __shared__ __align__(16) short Bs[BN * GBK];

    const int t    = threadIdx.x;
    const int wid  = t >> 6;
    const int lane = t & 63;

    const int cpx = gridDim.x >> 3;
    const int bid = blockIdx.x;
    const int wg  = (bid & 7) * cpx + (bid >> 3);
    const int nbx = N / BN;
    const int bx  = wg & (nbx - 1);
    const int by  = wg / nbx;

    const int row0 = by * BM;
    const int col0 = bx * BN;

    // staging: LDS linear (global_load_lds), swizzle applied on the GLOBAL source
    const int sr = t >> 2;
    const int ss = (t & 3) ^ ((sr >> 1) & 3);
    const short* Ag0 = A + (size_t)(row0 + sr) * K + ss * 8;
    const short* Ag1 = A + (size_t)(row0 + 64 + sr) * K + ss * 8;
    const short* Bg0 = B + (size_t)(col0 + sr) * K + ss * 8;
    const short* Bg1 = B + (size_t)(col0 + 64 + sr) * K + ss * 8;
    short* Al0 = &As[wid * 512];
    short* Al1 = &As[2048 + wid * 512];
    short* Bl0 = &Bs[wid * 512];
    short* Bl1 = &Bs[2048 + wid * 512];

    const int wr = wid >> 1, wc = wid & 1;

    f32x4 acc[4][4] = {};

    for (int k0 = 0; k0 < K; k0 += GBK) {
        gload16(Ag0 + k0, Al0);
        gload16(Ag1 + k0, Al1);
        gload16(Bg0 + k0, Bl0);
        gload16(Bg1 + k0, Bl1);
        __syncthreads();

        short8 af[4], bf[4];
#pragma unroll
        for (int i = 0; i < 4; ++i) {
            const int r  = wr * 64 + i * 16 + (lane & 15);
            const int sl = (lane >> 4) ^ ((r >> 1) & 3);
            af[i] = *reinterpret_cast<const short8*>(&As[r * GBK + sl * 8]);
        }
#pragma unroll
        for (int j = 0; j < 4; ++j) {
            const int r  = wc * 64 + j * 16 + (lane & 15);
            const int sl = (lane >> 4) ^ ((r >> 1) & 3);
            bf[j] = *reinterpret_cast<const short8*>(&Bs[r * GBK + sl * 8]);
        }
#pragma unroll
        for (int i = 0; i < 4; ++i)
#pragma unroll
            for (int j = 0; j < 4; ++j)
                acc[i][j] = __builtin_amdgcn_mfma_f32_16x16x32_bf16(
                    af[i], bf[j], acc[i][j], 0, 0, 0);
        __syncthreads();
    }

    float bv[4];
#pragma unroll
    for (int j = 0; j < 4; ++j) bv[j] = bias[col0 + wc * 64 + j * 16 + (lane & 15)];
#pragma unroll
    for (int i = 0; i < 4; ++i) {
        const int rbase = row0 + wr * 64 + i * 16 + (lane >> 4) * 4;
#pragma unroll
        for (int j = 0; j < 4; ++j) {
            const int col = col0 + wc * 64 + j * 16 + (lane & 15);
#pragma unroll
            for (int rg = 0; rg < 4; ++rg)
                C[(size_t)(rbase + rg) * N + col] = (acc[i][j][rg] + bv[j]) * scale;
        }
    }
}

// ---------------- fp32 fallback GEMM ----------------
#define TILE 64
#define BKK 16
#define PAD_LD 68

__global__ __launch_bounds__(256) void gemm_bt(
    const float* __restrict__ A, const float* __restrict__ W,
    const float* __restrict__ bias, float* __restrict__ C,
    int M, int K, int N, float scale)
{
    __shared__ float Asm[BKK][PAD_LD];
    __shared__ float Bsm[BKK][PAD_LD];
    const int t  = threadIdx.x;
    const int tx = t & 15;
    const int ty = t >> 4;
    const int row0 = blockIdx.y * TILE;
    const int col0 = blockIdx.x * TILE;
    const int lr = t >> 2;
    const int lk = (t & 3) << 2;
    const float* Aptr = A + (size_t)(row0 + lr) * K + lk;
    const float* Wptr = W + (size_t)(col0 + lr) * K + lk;
    float acc[4][4] = {};
    for (int k0 = 0; k0 < K; k0 += BKK) {
        float4 a4 = *reinterpret_cast<const float4*>(Aptr + k0);
        float4 b4 = *reinterpret_cast<const float4*>(Wptr + k0);
        Asm[lk + 0][lr] = a4.x; Asm[lk + 1][lr] = a4.y;
        Asm[lk + 2][lr] = a4.z; Asm[lk + 3][lr] = a4.w;
        Bsm[lk + 0][lr] = b4.x; Bsm[lk + 1][lr] = b4.y;
        Bsm[lk + 2][lr] = b4.z; Bsm[lk + 3][lr] = b4.w;
        __syncthreads();
#pragma unroll
        for (int kk = 0; kk < BKK; ++kk) {
            float a[4], b[4];
#pragma unroll
            for (int i2 = 0; i2 < 4; ++i2) a[i2] = Asm[kk][ty * 4 + i2];
#pragma unroll
            for (int j2 = 0; j2 < 4; ++j2) b[j2] = Bsm[kk][tx * 4 + j2];
#pragma unroll
            for (int i2 = 0; i2 < 4; ++i2)
#pragma unroll
                for (int j2 = 0; j2 < 4; ++j2)
                    acc[i2][j2] += a[i2] * b[j2];
        }
        __syncthreads();
    }
#pragma unroll
    for (int i2 = 0; i2 < 4; ++i2) {
        const int r = row0 + ty * 4 + i2;
        float4 o;
        o.x = (acc[i2][0] + bias[col0 + tx * 4 + 0]) * scale;
        o.y = (acc[i2][1] + bias[col0 + tx * 4 + 1]) * scale;
        o.z = (acc[i2][2] + bias[col0 + tx * 4 + 2]) * scale;
        o.w = (acc[i2][3] + bias[col0 + tx * 4 + 3]) * scale;
        *reinterpret_cast<float4*>(&C[(size_t)r * N + col0 + tx * 4]) = o;
    }
}

// ---------------- edge softmax/aggregate, v2 ----------------
// One block per node; wave = head. Lane = (g = lane>>4, c = lane&15):
// lane holds d-chunk [4c,4c+4) of edge rows {g, g+4, g+8, g+12} via float4 loads.
// QK: per-lane 4 partial dots -> reduce-scatter over lane bits 3,2 (3 shfl) +
// all-reduce bits 1,0 (2 shfl) => each lane one edge score e = g + 4*(2*b3+b2).
// Softmax: all-reduce max+sum over bits 2-5 (8 shfl), 1 exp/lane.
// PV: 4 shfl weight broadcast + float4 all-reduce over bits 4-5 (8 shfl).
// Output written as bf16 directly (feeds out-proj GEMM).
__global__ __launch_bounds__(512) void edge_attn2(
    const float* __restrict__ qmat, const float* __restrict__ kmat,
    const float* __restrict__ vmat, const int* __restrict__ colidx,
    short* __restrict__ outb)
{
    const int i    = blockIdx.x;
    const int h    = threadIdx.x >> 6;
    const int lane = threadIdx.x & 63;
    const int c    = lane & 15;
    const int g    = lane >> 4;

    int creg = 0;
    if (lane < DEG) creg = colidx[i * DEG + lane];
    int col[4];
#pragma unroll
    for (int e = 0; e < 4; ++e) col[e] = __shfl(creg, g + 4 * e, 64);

    const float4 qc = *reinterpret_cast<const float4*>(
        &qmat[(size_t)i * EMB + h * HDIM + 4 * c]);

    float4 kreg[4], vreg[4];
#pragma unroll
    for (int e = 0; e < 4; ++e)
        kreg[e] = *reinterpret_cast<const float4*>(
            &kmat[(size_t)col[e] * EMB + h * HDIM + 4 * c]);
#pragma unroll
    for (int e = 0; e < 4; ++e)
        vreg[e] = *reinterpret_cast<const float4*>(
            &vmat[(size_t)col[e] * EMB + h * HDIM + 4 * c]);

    float p[4];
#pragma unroll
    for (int e = 0; e < 4; ++e)
        p[e] = qc.x * kreg[e].x + qc.y * kreg[e].y +
               qc.z * kreg[e].z + qc.w * kreg[e].w;

    // reduce-scatter over bit 3 (keep 2 of 4 accumulators)
    const bool b3 = (lane & 8) != 0;
    float x0 = b3 ? p[0] : p[2];
    float x1 = b3 ? p[1] : p[3];
    float r0 = __shfl_xor(x0, 8, 64);
    float r1 = __shfl_xor(x1, 8, 64);
    float a0 = (b3 ? p[2] : p[0]) + r0;   // value index i = 2*b3
    float a1 = (b3 ? p[3] : p[1]) + r1;   // value index i = 2*b3+1

    // reduce-scatter over bit 2 (keep 1 of 2)
    const bool b2 = (lane & 4) != 0;
    float xx = b2 ? a0 : a1;
    float rr = __shfl_xor(xx, 4, 64);
    float s  = (b2 ? a1 : a0) + rr;       // value index i = 2*b3 + b2

    // all-reduce over bits 1,0 -> full 64-elem dot
    s += __shfl_xor(s, 1, 64);
    s += __shfl_xor(s, 2, 64);
    // lane holds score of edge e = g + 4*i

    // softmax over the 16 edges (distributed across lane bits 2-5)
    float m = s;
#pragma unroll
    for (int off = 4; off <= 32; off <<= 1) m = fmaxf(m, __shfl_xor(m, off, 64));
    float w = expf(s - m);
    float den = w;
#pragma unroll
    for (int off = 4; off <= 32; off <<= 1) den += __shfl_xor(den, off, 64);
    w *= (1.0f / den);

    // broadcast weights for this lane's 4 edge rows
    float wv[4];
#pragma unroll
    for (int e = 0; e < 4; ++e) {
        const int src = (lane & 48) | ((e >> 1) << 3) | ((e & 1) << 2);
        wv[e] = __shfl(w, src, 64);
    }

    float4 o = {0.f, 0.f, 0.f, 0.f};
#pragma unroll
    for (int e = 0; e < 4; ++e) {
        o.x += wv[e] * vreg[e].x; o.y += wv[e] * vreg[e].y;
        o.z += wv[e] * vreg[e].z; o.w += wv[e] * vreg[e].w;
    }

    // sum the 4 row-group partials (lane bits 4-5)
#pragma unroll
    for (int off = 16; off <= 32; off <<= 1) {
        o.x += __shfl_xor(o.x, off, 64);
        o.y += __shfl_xor(o.y, off, 64);
        o.z += __shfl_xor(o.z, off, 64);
        o.w += __shfl_xor(o.w, off, 64);
    }

    if (g == 0) {
        short4v ob;
        ob[0] = f2bs(o.x); ob[1] = f2bs(o.y);
        ob[2] = f2bs(o.z); ob[3] = f2bs(o.w);
        *reinterpret_cast<short4v*>(
            &outb[(size_t)i * EMB + h * HDIM + 4 * c]) = ob;
    }
}

// ---------------- fp32 fallback edge kernel ----------------
__global__ __launch_bounds__(512) void edge_attn(
    const float* q, const float* __restrict__ kmat, const float* __restrict__ vmat,
    const int* __restrict__ colidx, float* out)
{
    const int i    = blockIdx.x;
    const int h    = threadIdx.x >> 6;
    const int lane = threadIdx.x & 63;
    const size_t base = (size_t)i * EMB + h * HDIM + lane;

    const float qd = q[base];
    int creg = 0;
    if (lane < DEG) creg = colidx[i * DEG + lane];

    float kr[DEG], vr[DEG];
#pragma unroll
    for (int e = 0; e < DEG; ++e) {
        const int ce = __shfl(creg, e, 64);
        const size_t cb = (size_t)ce * EMB + h * HDIM + lane;
        kr[e] = kmat[cb];
        vr[e] = vmat[cb];
    }
    float s[DEG];
#pragma unroll
    for (int e = 0; e < DEG; ++e) {
        float p = qd * kr[e];
#pragma unroll
        for (int off = 32; off; off >>= 1) p += __shfl_xor(p, off, 64);
        s[e] = p;
    }
    float m = s[0];
#pragma unroll
    for (int e = 1; e < DEG; ++e) m = fmaxf(m, s[e]);
    float denom = 0.f;
#pragma unroll
    for (int e = 0; e < DEG; ++e) { s[e] = expf(s[e] - m); denom += s[e]; }
    const float inv = 1.f / denom;
    float o = 0.f;
#pragma unroll
    for (int e = 0; e < DEG; ++e) o += s[e] * vr[e];
    out[base] = o * inv;
}

extern "C" void kernel_launch(void* const* d_in, const int* in_sizes, int n_in,
                              void* d_out, int out_size, void* d_ws, size_t ws_size,
                              hipStream_t stream) {
    const float* query   = (const float*)d_in[0];
    const float* key_    = (const float*)d_in[1];
    const float* value   = (const float*)d_in[2];
    const int*   indices = (const int*)  d_in[3];
    const float* ipw     = (const float*)d_in[4];
    const float* ipb     = (const float*)d_in[5];
    const float* opw     = (const float*)d_in[6];
    const float* opb     = (const float*)d_in[7];
    float* out = (float*)d_out;

    const float scaling = 0.125f;
    const size_t NEED_BF16 = 153092096;

    if (ws_size >= NEED_BF16) {
        short* qb   = (short*)d_ws;
        short* kb   = qb + 8388608;
        short* vb   = kb + 8388608;
        short* wqkv = vb + 8388608;
        short* wo   = wqkv + 786432;
        float* qf   = (float*)((char*)d_ws + 52428800);
        float* kf   = qf + 8388608;
        float* vf   = kf + 8388608;

        f2b<<<2048, 256, 0, stream>>>(query, qb, 1048576);
        f2b<<<2048, 256, 0, stream>>>(key_,  kb, 1048576);
        f2b<<<2048, 256, 0, stream>>>(value, vb, 1048576);
        f2b<<<384,  256, 0, stream>>>(ipw, wqkv, 98304);
        f2b<<<128,  256, 0, stream>>>(opw, wo,   32768);

        gemm_bf16<<<512, 256, 0, stream>>>(qb, wqkv,          ipb,        qf,
                                           L_NODES, EMB, EMB, scaling);
        gemm_bf16<<<512, 256, 0, stream>>>(kb, wqkv + 262144, ipb + 512,  kf,
                                           L_NODES, EMB, EMB, 1.f);
        gemm_bf16<<<512, 256, 0, stream>>>(vb, wqkv + 524288, ipb + 1024, vf,
                                           L_NODES, EMB, EMB, 1.f);

        // writes bf16 attn directly into qb (query bf16 no longer needed)
        edge_attn2<<<L_NODES, 512, 0, stream>>>(qf, kf, vf, indices + NNZ_E, qb);

        gemm_bf16<<<512, 256, 0, stream>>>(qb, wo, opb, out, L_NODES, EMB, EMB, 1.f);
    } else {
        float* qbuf = (float*)d_ws;
        float* kbuf = qbuf + (size_t)L_NODES * EMB;
        float* vbuf = kbuf + (size_t)L_NODES * EMB;
        const dim3 gblk(EMB / TILE, L_NODES / TILE);
        gemm_bt<<<gblk, 256, 0, stream>>>(query, ipw,                 ipb,         qbuf,
                                          L_NODES, EMB, EMB, scaling);
        gemm_bt<<<gblk, 256, 0, stream>>>(key_,  ipw + 1 * EMB * EMB, ipb + EMB,   kbuf,
                                          L_NODES, EMB, EMB, 1.f);
        gemm_bt<<<gblk, 256, 0, stream>>>(value, ipw + 2 * EMB * EMB, ipb + 2*EMB, vbuf,
                                          L_NODES, EMB, EMB, 1.f);
        edge_attn<<<L_NODES, 512, 0, stream>>>(qbuf, kbuf, vbuf, indices + NNZ_E, qbuf);
        gemm_bt<<<gblk, 256, 0, stream>>>(qbuf, opw, opb, out, L_NODES, EMB, EMB, 1.f);
    }
}

// Round 6
// 170.699 us; speedup vs baseline: 4.3098x; 1.5151x over previous
//
#include <hip/hip_runtime.h>
#include <math.h>

#define L_NODES 16384
#define EMB 512
#define NHEAD 8
#define HDIM 64
#define DEG 16
#define NNZ_E (L_NODES * DEG)

typedef __attribute__((ext_vector_type(8))) short short8;
typedef __attribute__((ext_vector_type(4))) float f32x4;

// ---------------- fp32 -> bf16 convert (RNE) ----------------
__device__ inline short f2bs(float x) {
    union { float f; unsigned u; } c; c.f = x;
    unsigned r = (c.u + 0x7fffu + ((c.u >> 16) & 1u)) >> 16;
    return (short)r;
}

__device__ inline void cv8(const float* __restrict__ s, short* __restrict__ d, int i) {
    float4 a = reinterpret_cast<const float4*>(s)[2 * i];
    float4 b = reinterpret_cast<const float4*>(s)[2 * i + 1];
    short8 o;
    o[0] = f2bs(a.x); o[1] = f2bs(a.y); o[2] = f2bs(a.z); o[3] = f2bs(a.w);
    o[4] = f2bs(b.x); o[5] = f2bs(b.y); o[6] = f2bs(b.z); o[7] = f2bs(b.w);
    reinterpret_cast<short8*>(d)[i] = o;
}

__global__ __launch_bounds__(256) void f2b(const float* __restrict__ s,
                                           short* __restrict__ d, int n8) {
    const int stride = gridDim.x * blockDim.x;
    for (int i = blockIdx.x * blockDim.x + threadIdx.x; i < n8; i += stride)
        cv8(s, d, i);
}

// one launch converting query/key/value together
__global__ __launch_bounds__(256) void f2b3(
    const float* __restrict__ s0, const float* __restrict__ s1,
    const float* __restrict__ s2, short* __restrict__ d0,
    short* __restrict__ d1, short* __restrict__ d2, int n8) {
    const int stride = gridDim.x * blockDim.x;
    for (int i = blockIdx.x * blockDim.x + threadIdx.x; i < n8; i += stride) {
        cv8(s0, d0, i); cv8(s1, d1, i); cv8(s2, d2, i);
    }
}

// bf16x8 (as short8) -> 8 floats, order-preserving (little-endian)
__device__ inline void b2f8(short8 s, float* f) {
    const unsigned* u = reinterpret_cast<const unsigned*>(&s);
#pragma unroll
    for (int j = 0; j < 4; ++j) {
        unsigned lo = u[j] << 16;
        unsigned hi = u[j] & 0xFFFF0000u;
        f[2 * j]     = __builtin_bit_cast(float, lo);
        f[2 * j + 1] = __builtin_bit_cast(float, hi);
    }
}

// ---------------- bf16 MFMA GEMM: C = (A @ B^T + bias) * scale ----------------
// A: M x K bf16 row-major; B: N x K bf16 row-major. BOUT: write bf16 C.
#define BM 128
#define BN 128
#define GBK 32

__device__ inline void gload16(const short* g, short* l) {
    __builtin_amdgcn_global_load_lds(
        (const __attribute__((address_space(1))) unsigned*)g,
        (__attribute__((address_space(3))) unsigned*)l, 16, 0, 0);
}

template<bool BOUT>
__global__ __launch_bounds__(256) void gemm_bf16(
    const short* __restrict__ A, const short* __restrict__ B,
    const float* __restrict__ bias, void* __restrict__ Cout,
    int M, int K, int N, float scale)
{
    __shared__ __align__(16) short As[BM * GBK];
    __shared__ __align__(16) short Bs[BN * GBK];

    const int t    = threadIdx.x;
    const int wid  = t >> 6;
    const int lane = t & 63;

    const int cpx = gridDim.x >> 3;
    const int bid = blockIdx.x;
    const int wg  = (bid & 7) * cpx + (bid >> 3);
    const int nbx = N / BN;
    const int bx  = wg & (nbx - 1);
    const int by  = wg / nbx;

    const int row0 = by * BM;
    const int col0 = bx * BN;

    // staging: LDS linear (global_load_lds), swizzle applied on the GLOBAL source
    const int sr = t >> 2;
    const int ss = (t & 3) ^ ((sr >> 1) & 3);
    const short* Ag0 = A + (size_t)(row0 + sr) * K + ss * 8;
    const short* Ag1 = A + (size_t)(row0 + 64 + sr) * K + ss * 8;
    const short* Bg0 = B + (size_t)(col0 + sr) * K + ss * 8;
    const short* Bg1 = B + (size_t)(col0 + 64 + sr) * K + ss * 8;
    short* Al0 = &As[wid * 512];
    short* Al1 = &As[2048 + wid * 512];
    short* Bl0 = &Bs[wid * 512];
    short* Bl1 = &Bs[2048 + wid * 512];

    const int wr = wid >> 1, wc = wid & 1;

    f32x4 acc[4][4] = {};

    for (int k0 = 0; k0 < K; k0 += GBK) {
        gload16(Ag0 + k0, Al0);
        gload16(Ag1 + k0, Al1);
        gload16(Bg0 + k0, Bl0);
        gload16(Bg1 + k0, Bl1);
        __syncthreads();

        short8 af[4], bf[4];
#pragma unroll
        for (int i = 0; i < 4; ++i) {
            const int r  = wr * 64 + i * 16 + (lane & 15);
            const int sl = (lane >> 4) ^ ((r >> 1) & 3);
            af[i] = *reinterpret_cast<const short8*>(&As[r * GBK + sl * 8]);
        }
#pragma unroll
        for (int j = 0; j < 4; ++j) {
            const int r  = wc * 64 + j * 16 + (lane & 15);
            const int sl = (lane >> 4) ^ ((r >> 1) & 3);
            bf[j] = *reinterpret_cast<const short8*>(&Bs[r * GBK + sl * 8]);
        }
#pragma unroll
        for (int i = 0; i < 4; ++i)
#pragma unroll
            for (int j = 0; j < 4; ++j)
                acc[i][j] = __builtin_amdgcn_mfma_f32_16x16x32_bf16(
                    af[i], bf[j], acc[i][j], 0, 0, 0);
        __syncthreads();
    }

    float bv[4];
#pragma unroll
    for (int j = 0; j < 4; ++j) bv[j] = bias[col0 + wc * 64 + j * 16 + (lane & 15)];
#pragma unroll
    for (int i = 0; i < 4; ++i) {
        const int rbase = row0 + wr * 64 + i * 16 + (lane >> 4) * 4;
#pragma unroll
        for (int j = 0; j < 4; ++j) {
            const int col = col0 + wc * 64 + j * 16 + (lane & 15);
#pragma unroll
            for (int rg = 0; rg < 4; ++rg) {
                const float v = (acc[i][j][rg] + bv[j]) * scale;
                if constexpr (BOUT)
                    ((short*)Cout)[(size_t)(rbase + rg) * N + col] = f2bs(v);
                else
                    ((float*)Cout)[(size_t)(rbase + rg) * N + col] = v;
            }
        }
    }
}

// ---------------- fp32 fallback GEMM ----------------
#define TILE 64
#define BKK 16
#define PAD_LD 68

__global__ __launch_bounds__(256) void gemm_bt(
    const float* __restrict__ A, const float* __restrict__ W,
    const float* __restrict__ bias, float* __restrict__ C,
    int M, int K, int N, float scale)
{
    __shared__ float Asm[BKK][PAD_LD];
    __shared__ float Bsm[BKK][PAD_LD];
    const int t  = threadIdx.x;
    const int tx = t & 15;
    const int ty = t >> 4;
    const int row0 = blockIdx.y * TILE;
    const int col0 = blockIdx.x * TILE;
    const int lr = t >> 2;
    const int lk = (t & 3) << 2;
    const float* Aptr = A + (size_t)(row0 + lr) * K + lk;
    const float* Wptr = W + (size_t)(col0 + lr) * K + lk;
    float acc[4][4] = {};
    for (int k0 = 0; k0 < K; k0 += BKK) {
        float4 a4 = *reinterpret_cast<const float4*>(Aptr + k0);
        float4 b4 = *reinterpret_cast<const float4*>(Wptr + k0);
        Asm[lk + 0][lr] = a4.x; Asm[lk + 1][lr] = a4.y;
        Asm[lk + 2][lr] = a4.z; Asm[lk + 3][lr] = a4.w;
        Bsm[lk + 0][lr] = b4.x; Bsm[lk + 1][lr] = b4.y;
        Bsm[lk + 2][lr] = b4.z; Bsm[lk + 3][lr] = b4.w;
        __syncthreads();
#pragma unroll
        for (int kk = 0; kk < BKK; ++kk) {
            float a[4], b[4];
#pragma unroll
            for (int i2 = 0; i2 < 4; ++i2) a[i2] = Asm[kk][ty * 4 + i2];
#pragma unroll
            for (int j2 = 0; j2 < 4; ++j2) b[j2] = Bsm[kk][tx * 4 + j2];
#pragma unroll
            for (int i2 = 0; i2 < 4; ++i2)
#pragma unroll
                for (int j2 = 0; j2 < 4; ++j2)
                    acc[i2][j2] += a[i2] * b[j2];
        }
        __syncthreads();
    }
#pragma unroll
    for (int i2 = 0; i2 < 4; ++i2) {
        const int r = row0 + ty * 4 + i2;
        float4 o;
        o.x = (acc[i2][0] + bias[col0 + tx * 4 + 0]) * scale;
        o.y = (acc[i2][1] + bias[col0 + tx * 4 + 1]) * scale;
        o.z = (acc[i2][2] + bias[col0 + tx * 4 + 2]) * scale;
        o.w = (acc[i2][3] + bias[col0 + tx * 4 + 3]) * scale;
        *reinterpret_cast<float4*>(&C[(size_t)r * N + col0 + tx * 4]) = o;
    }
}

// ---------------- edge softmax/aggregate, v3 (bf16 gather) ----------------
// Block = node, wave = head. Lane = (g = lane>>3, c = lane&7).
// Lane owns edges {g, g+8} x d-chunk [8c, 8c+8): 2 K + 2 V + 1 Q short8 loads,
// zero redundancy on K/V. Score: per-lane partial dots -> reduce-scatter bit0
// + all-reduce bits 1,2 (edge e = g + 8*b0 per lane). Softmax over bits
// {0,3,4,5} (8 shfl, 1 exp). PV: 2-shfl weight bcast, fp32 accumulate,
// reduce-scatter over bits 3,4,5 (7 shfl) -> one output element per lane.
__global__ __launch_bounds__(512) void edge_attn3(
    const short* __restrict__ qm, const short* __restrict__ km,
    const short* __restrict__ vm, const int* __restrict__ colidx,
    short* __restrict__ outb)
{
    const int i    = blockIdx.x;
    const int h    = threadIdx.x >> 6;
    const int lane = threadIdx.x & 63;
    const int c    = lane & 7;
    const int g    = lane >> 3;

    int creg = 0;
    if (lane < DEG) creg = colidx[i * DEG + lane];
    const int col0 = __shfl(creg, g, 64);
    const int col1 = __shfl(creg, g + 8, 64);

    const size_t dof = (size_t)h * HDIM + 8 * c;
    short8 q8 = *reinterpret_cast<const short8*>(&qm[(size_t)i * EMB + dof]);
    short8 k0 = *reinterpret_cast<const short8*>(&km[(size_t)col0 * EMB + dof]);
    short8 k1 = *reinterpret_cast<const short8*>(&km[(size_t)col1 * EMB + dof]);
    short8 v0 = *reinterpret_cast<const short8*>(&vm[(size_t)col0 * EMB + dof]);
    short8 v1 = *reinterpret_cast<const short8*>(&vm[(size_t)col1 * EMB + dof]);

    float qf[8], kf0[8], kf1[8];
    b2f8(q8, qf); b2f8(k0, kf0); b2f8(k1, kf1);

    float p0 = 0.f, p1 = 0.f;
#pragma unroll
    for (int j = 0; j < 8; ++j) { p0 += qf[j] * kf0[j]; p1 += qf[j] * kf1[j]; }

    // reduce-scatter bit0: lane keeps edge e = g + 8*b0
    const bool b0 = (lane & 1) != 0;
    float x = b0 ? p0 : p1;
    float r = __shfl_xor(x, 1, 64);
    float s = (b0 ? p1 : p0) + r;
    // all-reduce bits 1,2 -> full 64-dim score
    s += __shfl_xor(s, 2, 64);
    s += __shfl_xor(s, 4, 64);

    // softmax over edge bits {0,3,4,5}
    float m = s;
    m = fmaxf(m, __shfl_xor(m, 1, 64));
    m = fmaxf(m, __shfl_xor(m, 8, 64));
    m = fmaxf(m, __shfl_xor(m, 16, 64));
    m = fmaxf(m, __shfl_xor(m, 32, 64));
    float w = expf(s - m);
    float den = w;
    den += __shfl_xor(den, 1, 64);
    den += __shfl_xor(den, 8, 64);
    den += __shfl_xor(den, 16, 64);
    den += __shfl_xor(den, 32, 64);
    w *= (1.0f / den);

    // weights for this lane's two edge rows
    const int srcb = lane & 56;
    const float w0 = __shfl(w, srcb, 64);       // edge g
    const float w1 = __shfl(w, srcb | 1, 64);   // edge g+8

    float vf0[8], vf1[8], of[8];
    b2f8(v0, vf0); b2f8(v1, vf1);
#pragma unroll
    for (int j = 0; j < 8; ++j) of[j] = w0 * vf0[j] + w1 * vf1[j];

    // reduce-scatter over g (bits 3,4,5): 4+2+1 shuffles
    const bool b3 = (lane & 8) != 0;
    float o4[4];
#pragma unroll
    for (int j = 0; j < 4; ++j) {
        float send = b3 ? of[j] : of[4 + j];
        float recv = __shfl_xor(send, 8, 64);
        o4[j] = (b3 ? of[4 + j] : of[j]) + recv;
    }
    const bool b4 = (lane & 16) != 0;
    float z0 = __shfl_xor(b4 ? o4[0] : o4[2], 16, 64);
    float z1 = __shfl_xor(b4 ? o4[1] : o4[3], 16, 64);
    float t0 = (b4 ? o4[2] : o4[0]) + z0;
    float t1 = (b4 ? o4[3] : o4[1]) + z1;
    const bool b5 = (lane & 32) != 0;
    float zz = __shfl_xor(b5 ? t0 : t1, 32, 64);
    float o1 = (b5 ? t1 : t0) + zz;

    const int d = 8 * c + (b3 ? 4 : 0) + (b4 ? 2 : 0) + (b5 ? 1 : 0);
    outb[(size_t)i * EMB + h * HDIM + d] = f2bs(o1);
}

// ---------------- fp32 fallback edge kernel ----------------
__global__ __launch_bounds__(512) void edge_attn(
    const float* q, const float* __restrict__ kmat, const float* __restrict__ vmat,
    const int* __restrict__ colidx, float* out)
{
    const int i    = blockIdx.x;
    const int h    = threadIdx.x >> 6;
    const int lane = threadIdx.x & 63;
    const size_t base = (size_t)i * EMB + h * HDIM + lane;

    const float qd = q[base];
    int creg = 0;
    if (lane < DEG) creg = colidx[i * DEG + lane];

    float kr[DEG], vr[DEG];
#pragma unroll
    for (int e = 0; e < DEG; ++e) {
        const int ce = __shfl(creg, e, 64);
        const size_t cb = (size_t)ce * EMB + h * HDIM + lane;
        kr[e] = kmat[cb];
        vr[e] = vmat[cb];
    }
    float s[DEG];
#pragma unroll
    for (int e = 0; e < DEG; ++e) {
        float p = qd * kr[e];
#pragma unroll
        for (int off = 32; off; off >>= 1) p += __shfl_xor(p, off, 64);
        s[e] = p;
    }
    float m = s[0];
#pragma unroll
    for (int e = 1; e < DEG; ++e) m = fmaxf(m, s[e]);
    float denom = 0.f;
#pragma unroll
    for (int e = 0; e < DEG; ++e) { s[e] = expf(s[e] - m); denom += s[e]; }
    const float inv = 1.f / denom;
    float o = 0.f;
#pragma unroll
    for (int e = 0; e < DEG; ++e) o += s[e] * vr[e];
    out[base] = o * inv;
}

extern "C" void kernel_launch(void* const* d_in, const int* in_sizes, int n_in,
                              void* d_out, int out_size, void* d_ws, size_t ws_size,
                              hipStream_t stream) {
    const float* query   = (const float*)d_in[0];
    const float* key_    = (const float*)d_in[1];
    const float* value   = (const float*)d_in[2];
    const int*   indices = (const int*)  d_in[3];
    const float* ipw     = (const float*)d_in[4];
    const float* ipb     = (const float*)d_in[5];
    const float* opw     = (const float*)d_in[6];
    const float* opb     = (const float*)d_in[7];
    float* out = (float*)d_out;

    const float scaling = 0.125f;
    const size_t NEED_BF16 = 153092096;

    if (ws_size >= NEED_BF16) {
        // bf16 workspace layout (shorts): 102.8 MB total
        short* qbi  = (short*)d_ws;          // query bf16 (later reused for attn out)
        short* kbi  = qbi + 8388608;
        short* vbi  = kbi + 8388608;
        short* wqkv = vbi + 8388608;
        short* wo   = wqkv + 786432;
        short* qo   = wo + 262144;           // q proj, bf16
        short* ko   = qo + 8388608;          // k proj, bf16
        short* vo   = ko + 8388608;          // v proj, bf16

        f2b3<<<2048, 256, 0, stream>>>(query, key_, value, qbi, kbi, vbi, 1048576);
        f2b<<<384,  256, 0, stream>>>(ipw, wqkv, 98304);
        f2b<<<128,  256, 0, stream>>>(opw, wo,   32768);

        gemm_bf16<true><<<512, 256, 0, stream>>>(qbi, wqkv,          ipb,        qo,
                                                 L_NODES, EMB, EMB, scaling);
        gemm_bf16<true><<<512, 256, 0, stream>>>(kbi, wqkv + 262144, ipb + 512,  ko,
                                                 L_NODES, EMB, EMB, 1.f);
        gemm_bf16<true><<<512, 256, 0, stream>>>(vbi, wqkv + 524288, ipb + 1024, vo,
                                                 L_NODES, EMB, EMB, 1.f);

        // bf16 gather + softmax; writes bf16 attn into qbi (query bf16 consumed)
        edge_attn3<<<L_NODES, 512, 0, stream>>>(qo, ko, vo, indices + NNZ_E, qbi);

        gemm_bf16<false><<<512, 256, 0, stream>>>(qbi, wo, opb, out,
                                                  L_NODES, EMB, EMB, 1.f);
    } else {
        float* qbuf = (float*)d_ws;
        float* kbuf = qbuf + (size_t)L_NODES * EMB;
        float* vbuf = kbuf + (size_t)L_NODES * EMB;
        const dim3 gblk(EMB / TILE, L_NODES / TILE);
        gemm_bt<<<gblk, 256, 0, stream>>>(query, ipw,                 ipb,         qbuf,
                                          L_NODES, EMB, EMB, scaling);
        gemm_bt<<<gblk, 256, 0, stream>>>(key_,  ipw + 1 * EMB * EMB, ipb + EMB,   kbuf,
                                          L_NODES, EMB, EMB, 1.f);
        gemm_bt<<<gblk, 256, 0, stream>>>(value, ipw + 2 * EMB * EMB, ipb + 2*EMB, vbuf,
                                          L_NODES, EMB, EMB, 1.f);
        edge_attn<<<L_NODES, 512, 0, stream>>>(qbuf, kbuf, vbuf, indices + NNZ_E, qbuf);
        gemm_bt<<<gblk, 256, 0, stream>>>(qbuf, opw, opb, out, L_NODES, EMB, EMB, 1.f);
    }
}

// Round 7
// 145.063 us; speedup vs baseline: 5.0714x; 1.1767x over previous
//
#include <hip/hip_runtime.h>
#include <math.h>

#define L_NODES 16384
#define EMB 512
#define NHEAD 8
#define HDIM 64
#define DEG 16
#define NNZ_E (L_NODES * DEG)

typedef __attribute__((ext_vector_type(8))) short short8;
typedef __attribute__((ext_vector_type(4))) float f32x4;

// ---------------- fp32 -> bf16 convert (RNE) ----------------
__device__ inline short f2bs(float x) {
    union { float f; unsigned u; } c; c.f = x;
    unsigned r = (c.u + 0x7fffu + ((c.u >> 16) & 1u)) >> 16;
    return (short)r;
}

__device__ inline void cv8(const float* __restrict__ s, short* __restrict__ d, int i) {
    float4 a = reinterpret_cast<const float4*>(s)[2 * i];
    float4 b = reinterpret_cast<const float4*>(s)[2 * i + 1];
    short8 o;
    o[0] = f2bs(a.x); o[1] = f2bs(a.y); o[2] = f2bs(a.z); o[3] = f2bs(a.w);
    o[4] = f2bs(b.x); o[5] = f2bs(b.y); o[6] = f2bs(b.z); o[7] = f2bs(b.w);
    reinterpret_cast<short8*>(d)[i] = o;
}

// both weight matrices in one launch
__global__ __launch_bounds__(256) void f2bw(
    const float* __restrict__ w1, short* __restrict__ d1, int n1,
    const float* __restrict__ w2, short* __restrict__ d2, int n2) {
    const int stride = gridDim.x * blockDim.x;
    for (int i = blockIdx.x * blockDim.x + threadIdx.x; i < n1 + n2; i += stride) {
        if (i < n1) cv8(w1, d1, i); else cv8(w2, d2, i - n1);
    }
}

// bf16x8 (as short8) -> 8 floats, order-preserving (little-endian)
__device__ inline void b2f8(short8 s, float* f) {
    const unsigned* u = reinterpret_cast<const unsigned*>(&s);
#pragma unroll
    for (int j = 0; j < 4; ++j) {
        unsigned lo = u[j] << 16;
        unsigned hi = u[j] & 0xFFFF0000u;
        f[2 * j]     = __builtin_bit_cast(float, lo);
        f[2 * j + 1] = __builtin_bit_cast(float, hi);
    }
}

#define BM 128
#define BN 128
#define GBK 32

__device__ inline void gload16(const short* g, short* l) {
    __builtin_amdgcn_global_load_lds(
        (const __attribute__((address_space(1))) unsigned*)g,
        (__attribute__((address_space(3))) unsigned*)l, 16, 0, 0);
}

// ---------------- fused QKV GEMM ----------------
// grid 1536: group w = blockIdx>>9 selects (input, weight slice, bias, out, scale).
// A fp32 is reg-staged + converted to bf16 in-kernel (swizzle on ds_write addr);
// B bf16 weights staged via global_load_lds (swizzle on global src addr).
__global__ __launch_bounds__(256) void gemm_qkv(
    const float* __restrict__ q_in, const float* __restrict__ k_in,
    const float* __restrict__ v_in, const short* __restrict__ wqkv,
    const float* __restrict__ bias_all,
    short* __restrict__ qo, short* __restrict__ ko, short* __restrict__ vo)
{
    __shared__ __align__(16) short As[BM * GBK];
    __shared__ __align__(16) short Bs[BN * GBK];

    const int gid   = blockIdx.x;
    const int which = gid >> 9;
    const int inner = gid & 511;

    const float* A    = which == 0 ? q_in : (which == 1 ? k_in : v_in);
    const short* B    = wqkv + which * 262144;
    const float* bias = bias_all + which * 512;
    short*       C    = which == 0 ? qo : (which == 1 ? ko : vo);
    const float scale = which == 0 ? 0.125f : 1.0f;

    const int t    = threadIdx.x;
    const int wid  = t >> 6;
    const int lane = t & 63;

    // XCD swizzle within each 512-block group
    const int wg = (inner & 7) * 64 + (inner >> 3);
    const int bx = wg & 3;
    const int by = wg >> 2;
    const int row0 = by * BM;
    const int col0 = bx * BN;

    // A staging: thread t covers row sr2 = t>>1, 16-float half kh
    const int sr2 = t >> 1;
    const int khf = (t & 1) << 4;                 // float offset 0 / 16
    const int xr  = (sr2 >> 1) & 3;
    const int p0  = (khf >> 3) ^ xr;              // physical slot of logical khf/8
    const int p1  = ((khf >> 3) + 1) ^ xr;
    const float* Agp = A + (size_t)(row0 + sr2) * 512 + khf;
    short* aw0 = &As[sr2 * GBK + p0 * 8];
    short* aw1 = &As[sr2 * GBK + p1 * 8];

    // B staging (global_load_lds, source-address swizzle)
    const int sr = t >> 2;
    const int ss = (t & 3) ^ ((sr >> 1) & 3);
    const short* Bg0 = B + (size_t)(col0 + sr) * 512 + ss * 8;
    const short* Bg1 = B + (size_t)(col0 + 64 + sr) * 512 + ss * 8;
    short* Bl0 = &Bs[wid * 512];
    short* Bl1 = &Bs[2048 + wid * 512];

    const int wr = wid >> 1, wc = wid & 1;

    f32x4 acc[4][4] = {};

    for (int k0 = 0; k0 < 512; k0 += GBK) {
        gload16(Bg0 + k0, Bl0);
        gload16(Bg1 + k0, Bl1);
        float4 a0 = *reinterpret_cast<const float4*>(Agp + k0);
        float4 a1 = *reinterpret_cast<const float4*>(Agp + k0 + 4);
        float4 a2 = *reinterpret_cast<const float4*>(Agp + k0 + 8);
        float4 a3 = *reinterpret_cast<const float4*>(Agp + k0 + 12);
        short8 s0, s1;
        s0[0] = f2bs(a0.x); s0[1] = f2bs(a0.y); s0[2] = f2bs(a0.z); s0[3] = f2bs(a0.w);
        s0[4] = f2bs(a1.x); s0[5] = f2bs(a1.y); s0[6] = f2bs(a1.z); s0[7] = f2bs(a1.w);
        s1[0] = f2bs(a2.x); s1[1] = f2bs(a2.y); s1[2] = f2bs(a2.z); s1[3] = f2bs(a2.w);
        s1[4] = f2bs(a3.x); s1[5] = f2bs(a3.y); s1[6] = f2bs(a3.z); s1[7] = f2bs(a3.w);
        *reinterpret_cast<short8*>(aw0) = s0;
        *reinterpret_cast<short8*>(aw1) = s1;
        __syncthreads();

        short8 af[4], bf[4];
#pragma unroll
        for (int i = 0; i < 4; ++i) {
            const int r  = wr * 64 + i * 16 + (lane & 15);
            const int sl = (lane >> 4) ^ ((r >> 1) & 3);
            af[i] = *reinterpret_cast<const short8*>(&As[r * GBK + sl * 8]);
        }
#pragma unroll
        for (int j = 0; j < 4; ++j) {
            const int r  = wc * 64 + j * 16 + (lane & 15);
            const int sl = (lane >> 4) ^ ((r >> 1) & 3);
            bf[j] = *reinterpret_cast<const short8*>(&Bs[r * GBK + sl * 8]);
        }
#pragma unroll
        for (int i = 0; i < 4; ++i)
#pragma unroll
            for (int j = 0; j < 4; ++j)
                acc[i][j] = __builtin_amdgcn_mfma_f32_16x16x32_bf16(
                    af[i], bf[j], acc[i][j], 0, 0, 0);
        __syncthreads();
    }

    float bv[4];
#pragma unroll
    for (int j = 0; j < 4; ++j) bv[j] = bias[col0 + wc * 64 + j * 16 + (lane & 15)];
#pragma unroll
    for (int i = 0; i < 4; ++i) {
        const int rbase = row0 + wr * 64 + i * 16 + (lane >> 4) * 4;
#pragma unroll
        for (int j = 0; j < 4; ++j) {
            const int col = col0 + wc * 64 + j * 16 + (lane & 15);
#pragma unroll
            for (int rg = 0; rg < 4; ++rg)
                C[(size_t)(rbase + rg) * 512 + col] =
                    f2bs((acc[i][j][rg] + bv[j]) * scale);
        }
    }
}

// ---------------- out-proj GEMM (bf16 A via global_load_lds, fp32 out) ----------------
__global__ __launch_bounds__(256) void gemm_out(
    const short* __restrict__ A, const short* __restrict__ B,
    const float* __restrict__ bias, float* __restrict__ C)
{
    __shared__ __align__(16) short As[BM * GBK];
    __shared__ __align__(16) short Bs[BN * GBK];

    const int t    = threadIdx.x;
    const int wid  = t >> 6;
    const int lane = t & 63;

    const int cpx = gridDim.x >> 3;
    const int bid = blockIdx.x;
    const int wg  = (bid & 7) * cpx + (bid >> 3);
    const int bx  = wg & 3;
    const int by  = wg >> 2;
    const int row0 = by * BM;
    const int col0 = bx * BN;

    const int sr = t >> 2;
    const int ss = (t & 3) ^ ((sr >> 1) & 3);
    const short* Ag0 = A + (size_t)(row0 + sr) * 512 + ss * 8;
    const short* Ag1 = A + (size_t)(row0 + 64 + sr) * 512 + ss * 8;
    const short* Bg0 = B + (size_t)(col0 + sr) * 512 + ss * 8;
    const short* Bg1 = B + (size_t)(col0 + 64 + sr) * 512 + ss * 8;
    short* Al0 = &As[wid * 512];
    short* Al1 = &As[2048 + wid * 512];
    short* Bl0 = &Bs[wid * 512];
    short* Bl1 = &Bs[2048 + wid * 512];

    const int wr = wid >> 1, wc = wid & 1;

    f32x4 acc[4][4] = {};

    for (int k0 = 0; k0 < 512; k0 += GBK) {
        gload16(Ag0 + k0, Al0);
        gload16(Ag1 + k0, Al1);
        gload16(Bg0 + k0, Bl0);
        gload16(Bg1 + k0, Bl1);
        __syncthreads();

        short8 af[4], bf[4];
#pragma unroll
        for (int i = 0; i < 4; ++i) {
            const int r  = wr * 64 + i * 16 + (lane & 15);
            const int sl = (lane >> 4) ^ ((r >> 1) & 3);
            af[i] = *reinterpret_cast<const short8*>(&As[r * GBK + sl * 8]);
        }
#pragma unroll
        for (int j = 0; j < 4; ++j) {
            const int r  = wc * 64 + j * 16 + (lane & 15);
            const int sl = (lane >> 4) ^ ((r >> 1) & 3);
            bf[j] = *reinterpret_cast<const short8*>(&Bs[r * GBK + sl * 8]);
        }
#pragma unroll
        for (int i = 0; i < 4; ++i)
#pragma unroll
            for (int j = 0; j < 4; ++j)
                acc[i][j] = __builtin_amdgcn_mfma_f32_16x16x32_bf16(
                    af[i], bf[j], acc[i][j], 0, 0, 0);
        __syncthreads();
    }

    float bv[4];
#pragma unroll
    for (int j = 0; j < 4; ++j) bv[j] = bias[col0 + wc * 64 + j * 16 + (lane & 15)];
#pragma unroll
    for (int i = 0; i < 4; ++i) {
        const int rbase = row0 + wr * 64 + i * 16 + (lane >> 4) * 4;
#pragma unroll
        for (int j = 0; j < 4; ++j) {
            const int col = col0 + wc * 64 + j * 16 + (lane & 15);
#pragma unroll
            for (int rg = 0; rg < 4; ++rg)
                C[(size_t)(rbase + rg) * 512 + col] = acc[i][j][rg] + bv[j];
        }
    }
}

// ---------------- edge softmax/aggregate, v4: 2 nodes/block ----------------
// Block handles nodes {2b, 2b+1}; wave = head for both. All 10 gathers issued
// before any reduction (2x MLP); two independent shuffle chains interleave.
__device__ inline float edge_core(const float* qf, short8 k0, short8 k1,
                                  short8 v0, short8 v1, int lane) {
    float kf0[8], kf1[8];
    b2f8(k0, kf0); b2f8(k1, kf1);
    float p0 = 0.f, p1 = 0.f;
#pragma unroll
    for (int j = 0; j < 8; ++j) { p0 += qf[j] * kf0[j]; p1 += qf[j] * kf1[j]; }

    const bool b0 = (lane & 1) != 0;
    float x = b0 ? p0 : p1;
    float r = __shfl_xor(x, 1, 64);
    float s = (b0 ? p1 : p0) + r;
    s += __shfl_xor(s, 2, 64);
    s += __shfl_xor(s, 4, 64);

    float m = s;
    m = fmaxf(m, __shfl_xor(m, 1, 64));
    m = fmaxf(m, __shfl_xor(m, 8, 64));
    m = fmaxf(m, __shfl_xor(m, 16, 64));
    m = fmaxf(m, __shfl_xor(m, 32, 64));
    float w = expf(s - m);
    float den = w;
    den += __shfl_xor(den, 1, 64);
    den += __shfl_xor(den, 8, 64);
    den += __shfl_xor(den, 16, 64);
    den += __shfl_xor(den, 32, 64);
    w *= (1.0f / den);

    const int srcb = lane & 56;
    const float w0 = __shfl(w, srcb, 64);
    const float w1 = __shfl(w, srcb | 1, 64);

    float vf0[8], vf1[8], of[8];
    b2f8(v0, vf0); b2f8(v1, vf1);
#pragma unroll
    for (int j = 0; j < 8; ++j) of[j] = w0 * vf0[j] + w1 * vf1[j];

    const bool b3 = (lane & 8) != 0;
    float o4[4];
#pragma unroll
    for (int j = 0; j < 4; ++j) {
        float send = b3 ? of[j] : of[4 + j];
        float recv = __shfl_xor(send, 8, 64);
        o4[j] = (b3 ? of[4 + j] : of[j]) + recv;
    }
    const bool b4 = (lane & 16) != 0;
    float z0 = __shfl_xor(b4 ? o4[0] : o4[2], 16, 64);
    float z1 = __shfl_xor(b4 ? o4[1] : o4[3], 16, 64);
    float t0 = (b4 ? o4[2] : o4[0]) + z0;
    float t1 = (b4 ? o4[3] : o4[1]) + z1;
    const bool b5 = (lane & 32) != 0;
    float zz = __shfl_xor(b5 ? t0 : t1, 32, 64);
    return (b5 ? t1 : t0) + zz;
}

__global__ __launch_bounds__(512) void edge_attn4(
    const short* __restrict__ qm, const short* __restrict__ km,
    const short* __restrict__ vm, const int* __restrict__ colidx,
    short* __restrict__ outb)
{
    const int i0   = blockIdx.x << 1;
    const int h    = threadIdx.x >> 6;
    const int lane = threadIdx.x & 63;
    const int c    = lane & 7;
    const int g    = lane >> 3;

    int creg = 0;
    if (lane < 2 * DEG) creg = colidx[i0 * DEG + lane];
    const int ca0 = __shfl(creg, g, 64);
    const int ca1 = __shfl(creg, g + 8, 64);
    const int cb0 = __shfl(creg, 16 + g, 64);
    const int cb1 = __shfl(creg, 16 + g + 8, 64);

    const size_t dof = (size_t)h * HDIM + 8 * c;
    short8 qA  = *reinterpret_cast<const short8*>(&qm[(size_t)i0 * EMB + dof]);
    short8 qB  = *reinterpret_cast<const short8*>(&qm[(size_t)(i0 + 1) * EMB + dof]);
    short8 kA0 = *reinterpret_cast<const short8*>(&km[(size_t)ca0 * EMB + dof]);
    short8 kA1 = *reinterpret_cast<const short8*>(&km[(size_t)ca1 * EMB + dof]);
    short8 kB0 = *reinterpret_cast<const short8*>(&km[(size_t)cb0 * EMB + dof]);
    short8 kB1 = *reinterpret_cast<const short8*>(&km[(size_t)cb1 * EMB + dof]);
    short8 vA0 = *reinterpret_cast<const short8*>(&vm[(size_t)ca0 * EMB + dof]);
    short8 vA1 = *reinterpret_cast<const short8*>(&vm[(size_t)ca1 * EMB + dof]);
    short8 vB0 = *reinterpret_cast<const short8*>(&vm[(size_t)cb0 * EMB + dof]);
    short8 vB1 = *reinterpret_cast<const short8*>(&vm[(size_t)cb1 * EMB + dof]);

    float qfA[8], qfB[8];
    b2f8(qA, qfA); b2f8(qB, qfB);

    const float oA = edge_core(qfA, kA0, kA1, vA0, vA1, lane);
    const float oB = edge_core(qfB, kB0, kB1, vB0, vB1, lane);

    const int d = 8 * c + ((lane & 8) ? 4 : 0) + ((lane & 16) ? 2 : 0)
                        + ((lane & 32) ? 1 : 0);
    outb[(size_t)i0 * EMB + h * HDIM + d]       = f2bs(oA);
    outb[(size_t)(i0 + 1) * EMB + h * HDIM + d] = f2bs(oB);
}

// ---------------- fp32 fallback path ----------------
#define TILE 64
#define BKK 16
#define PAD_LD 68

__global__ __launch_bounds__(256) void gemm_bt(
    const float* __restrict__ A, const float* __restrict__ W,
    const float* __restrict__ bias, float* __restrict__ C,
    int M, int K, int N, float scale)
{
    __shared__ float Asm[BKK][PAD_LD];
    __shared__ float Bsm[BKK][PAD_LD];
    const int t  = threadIdx.x;
    const int tx = t & 15;
    const int ty = t >> 4;
    const int row0 = blockIdx.y * TILE;
    const int col0 = blockIdx.x * TILE;
    const int lr = t >> 2;
    const int lk = (t & 3) << 2;
    const float* Aptr = A + (size_t)(row0 + lr) * K + lk;
    const float* Wptr = W + (size_t)(col0 + lr) * K + lk;
    float acc[4][4] = {};
    for (int k0 = 0; k0 < K; k0 += BKK) {
        float4 a4 = *reinterpret_cast<const float4*>(Aptr + k0);
        float4 b4 = *reinterpret_cast<const float4*>(Wptr + k0);
        Asm[lk + 0][lr] = a4.x; Asm[lk + 1][lr] = a4.y;
        Asm[lk + 2][lr] = a4.z; Asm[lk + 3][lr] = a4.w;
        Bsm[lk + 0][lr] = b4.x; Bsm[lk + 1][lr] = b4.y;
        Bsm[lk + 2][lr] = b4.z; Bsm[lk + 3][lr] = b4.w;
        __syncthreads();
#pragma unroll
        for (int kk = 0; kk < BKK; ++kk) {
            float a[4], b[4];
#pragma unroll
            for (int i2 = 0; i2 < 4; ++i2) a[i2] = Asm[kk][ty * 4 + i2];
#pragma unroll
            for (int j2 = 0; j2 < 4; ++j2) b[j2] = Bsm[kk][tx * 4 + j2];
#pragma unroll
            for (int i2 = 0; i2 < 4; ++i2)
#pragma unroll
                for (int j2 = 0; j2 < 4; ++j2)
                    acc[i2][j2] += a[i2] * b[j2];
        }
        __syncthreads();
    }
#pragma unroll
    for (int i2 = 0; i2 < 4; ++i2) {
        const int r = row0 + ty * 4 + i2;
        float4 o;
        o.x = (acc[i2][0] + bias[col0 + tx * 4 + 0]) * scale;
        o.y = (acc[i2][1] + bias[col0 + tx * 4 + 1]) * scale;
        o.z = (acc[i2][2] + bias[col0 + tx * 4 + 2]) * scale;
        o.w = (acc[i2][3] + bias[col0 + tx * 4 + 3]) * scale;
        *reinterpret_cast<float4*>(&C[(size_t)r * N + col0 + tx * 4]) = o;
    }
}

__global__ __launch_bounds__(512) void edge_attn(
    const float* q, const float* __restrict__ kmat, const float* __restrict__ vmat,
    const int* __restrict__ colidx, float* out)
{
    const int i    = blockIdx.x;
    const int h    = threadIdx.x >> 6;
    const int lane = threadIdx.x & 63;
    const size_t base = (size_t)i * EMB + h * HDIM + lane;

    const float qd = q[base];
    int creg = 0;
    if (lane < DEG) creg = colidx[i * DEG + lane];

    float kr[DEG], vr[DEG];
#pragma unroll
    for (int e = 0; e < DEG; ++e) {
        const int ce = __shfl(creg, e, 64);
        const size_t cb = (size_t)ce * EMB + h * HDIM + lane;
        kr[e] = kmat[cb];
        vr[e] = vmat[cb];
    }
    float s[DEG];
#pragma unroll
    for (int e = 0; e < DEG; ++e) {
        float p = qd * kr[e];
#pragma unroll
        for (int off = 32; off; off >>= 1) p += __shfl_xor(p, off, 64);
        s[e] = p;
    }
    float m = s[0];
#pragma unroll
    for (int e = 1; e < DEG; ++e) m = fmaxf(m, s[e]);
    float denom = 0.f;
#pragma unroll
    for (int e = 0; e < DEG; ++e) { s[e] = expf(s[e] - m); denom += s[e]; }
    const float inv = 1.f / denom;
    float o = 0.f;
#pragma unroll
    for (int e = 0; e < DEG; ++e) o += s[e] * vr[e];
    out[base] = o * inv;
}

extern "C" void kernel_launch(void* const* d_in, const int* in_sizes, int n_in,
                              void* d_out, int out_size, void* d_ws, size_t ws_size,
                              hipStream_t stream) {
    const float* query   = (const float*)d_in[0];
    const float* key_    = (const float*)d_in[1];
    const float* value   = (const float*)d_in[2];
    const int*   indices = (const int*)  d_in[3];
    const float* ipw     = (const float*)d_in[4];
    const float* ipb     = (const float*)d_in[5];
    const float* opw     = (const float*)d_in[6];
    const float* opb     = (const float*)d_in[7];
    float* out = (float*)d_out;

    const size_t NEED = 70000000;  // shorts: wqkv+wo+qo+ko+vo+ab = 69.2 MB

    if (ws_size >= NEED) {
        short* wqkv = (short*)d_ws;          // 786432
        short* wo   = wqkv + 786432;         // 262144
        short* qo   = wo + 262144;           // 8388608 each
        short* ko   = qo + 8388608;
        short* vo   = ko + 8388608;
        short* ab   = vo + 8388608;          // attn out bf16

        f2bw<<<512, 256, 0, stream>>>(ipw, wqkv, 98304, opw, wo, 32768);
        gemm_qkv<<<1536, 256, 0, stream>>>(query, key_, value, wqkv, ipb,
                                           qo, ko, vo);
        edge_attn4<<<L_NODES / 2, 512, 0, stream>>>(qo, ko, vo,
                                                    indices + NNZ_E, ab);
        gemm_out<<<512, 256, 0, stream>>>(ab, wo, opb, out);
    } else {
        float* qbuf = (float*)d_ws;
        float* kbuf = qbuf + (size_t)L_NODES * EMB;
        float* vbuf = kbuf + (size_t)L_NODES * EMB;
        const dim3 gblk(EMB / TILE, L_NODES / TILE);
        const float scaling = 0.125f;
        gemm_bt<<<gblk, 256, 0, stream>>>(query, ipw,                 ipb,         qbuf,
                                          L_NODES, EMB, EMB, scaling);
        gemm_bt<<<gblk, 256, 0, stream>>>(key_,  ipw + 1 * EMB * EMB, ipb + EMB,   kbuf,
                                          L_NODES, EMB, EMB, 1.f);
        gemm_bt<<<gblk, 256, 0, stream>>>(value, ipw + 2 * EMB * EMB, ipb + 2*EMB, vbuf,
                                          L_NODES, EMB, EMB, 1.f);
        edge_attn<<<L_NODES, 512, 0, stream>>>(qbuf, kbuf, vbuf, indices + NNZ_E, qbuf);
        gemm_bt<<<gblk, 256, 0, stream>>>(qbuf, opw, opb, out, L_NODES, EMB, EMB, 1.f);
    }
}